// Round 4
// baseline (370.029 us; speedup 1.0000x reference)
//
#include <hip/hip_runtime.h>

// MLLoss: per-row hinge-margin loss over [B,16] fp32 distances, label-selected,
// mean-reduced to a scalar. Memory-bound: 256 MB distances + 32 MB labels.
//
// R4: contiguous-per-block partitioning. R3's grid-stride loop had a 16 MB
// iteration stride -> 16K waves each walking scattered 1 KB chunks = DRAM
// row-buffer/page thrash (~2.7 TB/s effective). Now each block owns one
// contiguous 64 KB distance range walked in 4 KB steps (like the 6.6 TB/s
// harness fills), giving 4K sequential streams chip-wide.
//
// Layout: 4 lanes per row ("quad"), each lane loads one 16 B vector so every
// wave load is 1 KB contiguous. hinge_sum reduced in-quad with 2 shfl_xor.
// All 4 quad lanes load the row's labels (same addr -> HW broadcast), control
// flow uniform, #pragma unroll 4 -> 4 independent load chains per thread.
// Phase 1 writes one pre-scaled partial per block to d_ws; phase 2 (1 block)
// reduces partials and stores the scalar -> no memset, no atomics.

typedef float vfloat4 __attribute__((ext_vector_type(4)));

#define BLOCKS  4096
#define THREADS 256

__global__ __launch_bounds__(THREADS) void mlloss_partial(
    const vfloat4* __restrict__ dist4,  // B*4 vfloat4 (16 floats/row)
    const int*     __restrict__ doctor, // [B] 0=control 1=parkinson 2=unknown
    const int*     __restrict__ real,   // [B] 0=control 1=parkinson
    float* __restrict__ partials,       // [gridDim.x]
    int B, float invB)
{
    // Each block owns a contiguous range of rows (B assumed divisible by
    // gridDim.x; guard keeps the tail correct anyway).
    const int rows_per_block = (B + (int)gridDim.x - 1) / (int)gridDim.x;
    const int row0   = blockIdx.x * rows_per_block;
    const int rend   = min(row0 + rows_per_block, B);
    const int lane4  = threadIdx.x & 3;              // vector index within row
    const int qstep  = THREADS >> 2;                 // 64 rows per block-iter

    float acc = 0.0f;

    #pragma unroll 4
    for (int q = row0 + (threadIdx.x >> 2); q < rend; q += qstep) {
        vfloat4 d = __builtin_nontemporal_load(&dist4[(size_t)q * 4 + lane4]);
        int doc   = doctor[q];                       // same addr for all
        int re    = real[q];                         // 4 quad lanes

        float h0 = fmaxf(1.0f - d.x, 0.0f);
        float h1 = fmaxf(1.0f - d.y, 0.0f);
        float h2 = fmaxf(1.0f - d.z, 0.0f);
        float h3 = fmaxf(1.0f - d.w, 0.0f);
        float s  = (h0 + h1) + (h2 + h3);

        // hinge_sum across the 4 lanes of this quad
        s += __shfl_xor(s, 1);
        s += __shfl_xor(s, 2);

        // lane with lane4==0 holds row elements 0..3: d.x=d[0], d.y=d[1]
        float loss_c = d.x + s - h0;                 // doctor == control
        float loss_p = d.y + s - h1;                 // doctor == parkinson
        float loss_u = (re == 0) ? h1 : h0;          // doctor == unknown
        float loss   = (doc == 0) ? loss_c : ((doc == 1) ? loss_p : loss_u);
        acc += (lane4 == 0) ? loss : 0.0f;
    }

    // wave (64-lane) reduction
    #pragma unroll
    for (int m = 32; m >= 1; m >>= 1)
        acc += __shfl_xor(acc, m);

    __shared__ float wsum[THREADS / 64];
    const int wid = threadIdx.x >> 6;
    if ((threadIdx.x & 63) == 0) wsum[wid] = acc;
    __syncthreads();

    if (threadIdx.x == 0) {
        float t = 0.0f;
        #pragma unroll
        for (int w = 0; w < THREADS / 64; ++w) t += wsum[w];
        partials[blockIdx.x] = t * invB;             // pre-scaled, ~1e-3 each
    }
}

__global__ __launch_bounds__(THREADS) void mlloss_final(
    const float* __restrict__ partials, float* __restrict__ out, int n)
{
    float acc = 0.0f;
    for (int i = threadIdx.x; i < n; i += THREADS)
        acc += partials[i];

    #pragma unroll
    for (int m = 32; m >= 1; m >>= 1)
        acc += __shfl_xor(acc, m);

    __shared__ float wsum[THREADS / 64];
    const int wid = threadIdx.x >> 6;
    if ((threadIdx.x & 63) == 0) wsum[wid] = acc;
    __syncthreads();

    if (threadIdx.x == 0) {
        float t = 0.0f;
        #pragma unroll
        for (int w = 0; w < THREADS / 64; ++w) t += wsum[w];
        out[0] = t;
    }
}

extern "C" void kernel_launch(void* const* d_in, const int* in_sizes, int n_in,
                              void* d_out, int out_size, void* d_ws, size_t ws_size,
                              hipStream_t stream) {
    const vfloat4* dist4  = (const vfloat4*)d_in[0];
    const int*     doctor = (const int*)d_in[1];
    const int*     real_l = (const int*)d_in[2];
    float*         out    = (float*)d_out;
    float*         part   = (float*)d_ws;  // 4096 floats = 16 KB scratch

    const int B = in_sizes[1];             // doctor_labels element count

    mlloss_partial<<<BLOCKS, THREADS, 0, stream>>>(
        dist4, doctor, real_l, part, B, 1.0f / (float)B);
    mlloss_final<<<1, THREADS, 0, stream>>>(part, out, BLOCKS);
}